// Round 5
// baseline (75.463 us; speedup 1.0000x reference)
//
#include <hip/hip_runtime.h>
#include <math.h>

#define NPART 2048
#define MI    2               // i-particles per thread (register tile)
#define IPB   16              // 8 wave-groups * MI
#define BLOCK 512             // 8 waves; j-split = 64 (full wave)

// Log-spaced lookup table for fr(d2), indexed by float bits of d2.
// idx = clamp((bits(d2) >> 17) - TBASE, 0, TABN-1): 6 mantissa bits + exponent,
// covers d2 in [2^-20, 1.0) (scaled coords: d2 <= 0.75).
#define TABN  1280
#define TBASE 6848            // 107 << 6  (exponent for 2^-20)

// Backflow in scaled coords u = x/L in [0,1):
//   du -= rint(du)  (min image)
//   fr(d2) = 0.5*(exp(-(b2s/d2)^2.5) - 1),  b2s = (2.6/L)^2   [via LDS table]
//   out = L * (u_i + sum_j fr * du)
// Self-pair: d2=0 -> bits=0 -> idx clamps to 0 -> fr=-0.5, du=0 -> 0. No NaN/Inf.
__global__ __launch_bounds__(BLOCK, 4)
void backflow_kernel(const float* __restrict__ x, float* __restrict__ out,
                     float L, float invL, float b2s) {
    __shared__ float4 ps[NPART];    // 32 KB scaled positions
    __shared__ float  gtab[TABN];   // 5 KB fr(d2) table

    const int tid   = threadIdx.x;
    const int blk   = blockIdx.x;
    const int b     = blk >> 7;             // 8 batches x 128 blocks
    const int ibase = (blk & 127) * IPB;
    const float* xb = x + b * (NPART * 3);

    // Build fr table (2.5 entries/thread; off the critical path)
    for (int e = tid; e < TABN; e += BLOCK) {
        int   bits = ((e + TBASE) << 17) | 0x10000;   // bin center
        float d2c  = __int_as_float(bits);
        float t5   = powf(b2s / d2c, 2.5f);           // (2.6/d)^5, finite
        gtab[e] = 0.5f * (expf(-t5) - 1.0f);
    }

    // Stage scaled positions: u = frac(x * invL)
    for (int p = tid; p < NPART; p += BLOCK) {
        float ux = xb[3 * p + 0] * invL;
        float uy = xb[3 * p + 1] * invL;
        float uz = xb[3 * p + 2] * invL;
        ux -= floorf(ux);
        uy -= floorf(uy);
        uz -= floorf(uz);
        ps[p] = make_float4(ux, uy, uz, 0.0f);
    }
    __syncthreads();

    const int lane = tid & 63;              // j-split across the full wave
    const int g    = tid >> 6;              // 0..7
    const int i0   = ibase + g * MI;

    const float4 pi0 = ps[i0];              // wave-uniform broadcast reads
    const float4 pi1 = ps[i0 + 1];

    float ax0 = 0.f, ay0 = 0.f, az0 = 0.f;
    float ax1 = 0.f, ay1 = 0.f, az1 = 0.f;

    #pragma unroll 2
    for (int k = 0; k < NPART / 64; ++k) {
        const int j = lane + (k << 6);
        const float4 pj = ps[j];            // contiguous b128, conflict-free

        // pair (i0, j)
        float dx = pi0.x - pj.x, dy = pi0.y - pj.y, dz = pi0.z - pj.z;
        dx -= rintf(dx);  dy -= rintf(dy);  dz -= rintf(dz);
        float d2 = fmaf(dx, dx, fmaf(dy, dy, dz * dz));
        int idx0 = (__float_as_int(d2) >> 17) - TBASE;
        idx0 = idx0 < 0 ? 0 : idx0;         // v_max_i32 (d2<=0.75 -> no high clamp)
        float fr = gtab[idx0];              // LDS gather (random banks, ~1.6x)
        ax0 = fmaf(fr, dx, ax0); ay0 = fmaf(fr, dy, ay0); az0 = fmaf(fr, dz, az0);

        // pair (i0+1, j) — independent chain
        float ex = pi1.x - pj.x, ey = pi1.y - pj.y, ez = pi1.z - pj.z;
        ex -= rintf(ex);  ey -= rintf(ey);  ez -= rintf(ez);
        float e2 = fmaf(ex, ex, fmaf(ey, ey, ez * ez));
        int idx1 = (__float_as_int(e2) >> 17) - TBASE;
        idx1 = idx1 < 0 ? 0 : idx1;
        float fs = gtab[idx1];
        ax1 = fmaf(fs, ex, ax1); ay1 = fmaf(fs, ey, ay1); az1 = fmaf(fs, ez, az1);
    }

    // full-wave reduction (64 lanes -> lane 0)
    #pragma unroll
    for (int off = 32; off >= 1; off >>= 1) {
        ax0 += __shfl_xor(ax0, off); ay0 += __shfl_xor(ay0, off); az0 += __shfl_xor(az0, off);
        ax1 += __shfl_xor(ax1, off); ay1 += __shfl_xor(ay1, off); az1 += __shfl_xor(az1, off);
    }

    if (lane == 0) {
        float* o0 = out + (b * NPART + i0) * 3;
        o0[0] = L * (pi0.x + ax0);
        o0[1] = L * (pi0.y + ay0);
        o0[2] = L * (pi0.z + az0);
        o0[3] = L * (pi1.x + ax1);
        o0[4] = L * (pi1.y + ay1);
        o0[5] = L * (pi1.z + az1);
    }
}

extern "C" void kernel_launch(void* const* d_in, const int* in_sizes, int n_in,
                              void* d_out, int out_size, void* d_ws, size_t ws_size,
                              hipStream_t stream) {
    (void)in_sizes; (void)n_in; (void)d_ws; (void)ws_size; (void)out_size;
    const float* x = (const float*)d_in[0];
    float* out     = (float*)d_out;

    const double Ld   = cbrt(2048.0 / 0.016355);
    const double t    = 2.6 / Ld;
    const float  L    = (float)Ld;
    const float  invL = (float)(1.0 / Ld);
    const float  b2s  = (float)(t * t);     // (2.6/L)^2 in scaled units

    const int nblocks = (8 * NPART) / IPB;  // 1024
    backflow_kernel<<<nblocks, BLOCK, 0, stream>>>(x, out, L, invL, b2s);
}

// Round 6
// 73.649 us; speedup vs baseline: 1.0246x; 1.0246x over previous
//
#include <hip/hip_runtime.h>
#include <math.h>

#define NPART 2048
#define MI    4               // i-particles per thread (ILP chains)
#define GRPS  8               // wave-groups per block
#define IPB   (GRPS * MI)     // 32 i-particles per block
#define BLOCK 512             // 8 waves; j-split = 64 (full wave)

#if __has_builtin(__builtin_amdgcn_rsqf)
#define RSQF(x) __builtin_amdgcn_rsqf(x)
#else
#define RSQF(x) rsqrtf(x)
#endif
#if __has_builtin(__builtin_amdgcn_exp2f)
#define EXP2F(x) __builtin_amdgcn_exp2f(x)
#else
#define EXP2F(x) exp2f(x)
#endif

// Scaled-coordinate backflow: u = x/L in [0,1).
//   min-image: du -= rint(du)
//   fr = 0.5*(exp2(K * (1/|du|)^5) - 1),  K = -log2(e)*(2.6/L)^5
//   out = L * (u_i + sum_j fr * du)
// Self-pair: d2=0 -> ri=inf -> K*ri^5=-inf -> exp2=0 -> fr=-0.5, fr*0=0. No NaN.
__global__ __launch_bounds__(BLOCK, 4)
void backflow_kernel(const float* __restrict__ x, float* __restrict__ out,
                     float L, float invL, float K) {
    __shared__ float4 ps[NPART];   // 32 KB scaled positions

    const int tid   = threadIdx.x;
    const int blk   = blockIdx.x;
    const int b     = blk >> 6;            // 8 batches x 64 blocks
    const int ibase = (blk & 63) * IPB;
    const float* xb = x + b * (NPART * 3);

    for (int p = tid; p < NPART; p += BLOCK) {
        float ux = xb[3 * p + 0] * invL;
        float uy = xb[3 * p + 1] * invL;
        float uz = xb[3 * p + 2] * invL;
        ux -= floorf(ux);
        uy -= floorf(uy);
        uz -= floorf(uz);
        ps[p] = make_float4(ux, uy, uz, 0.0f);
    }
    __syncthreads();

    const int lane = tid & 63;             // j-split across the full wave
    const int g    = tid >> 6;             // 0..7
    const int i0   = ibase + g * MI;

    float4 pi[MI];
    float  ax[MI], ay[MI], az[MI];
    #pragma unroll
    for (int m = 0; m < MI; ++m) {         // static indices only (no scratch)
        pi[m] = ps[i0 + m];                // wave-uniform broadcast reads
        ax[m] = 0.f; ay[m] = 0.f; az[m] = 0.f;
    }

    #pragma unroll 2
    for (int k = 0; k < NPART / 64; ++k) {
        const float4 pj = ps[lane + (k << 6)];  // contiguous b128, conflict-free
        #pragma unroll
        for (int m = 0; m < MI; ++m) {     // 4 independent chains per b128 read
            float dx = pi[m].x - pj.x, dy = pi[m].y - pj.y, dz = pi[m].z - pj.z;
            dx -= rintf(dx);  dy -= rintf(dy);  dz -= rintf(dz);
            float d2  = fmaf(dx, dx, fmaf(dy, dy, dz * dz));
            float ri  = RSQF(d2);
            float ri2 = ri * ri;
            float ri4 = ri2 * ri2;
            float fr  = fmaf(0.5f, EXP2F((K * ri4) * ri), -0.5f);
            ax[m] = fmaf(fr, dx, ax[m]);
            ay[m] = fmaf(fr, dy, ay[m]);
            az[m] = fmaf(fr, dz, az[m]);
        }
    }

    // full-wave reduction (64 lanes -> lane 0), 12 accumulators, once per thread
    #pragma unroll
    for (int off = 32; off >= 1; off >>= 1) {
        #pragma unroll
        for (int m = 0; m < MI; ++m) {
            ax[m] += __shfl_xor(ax[m], off);
            ay[m] += __shfl_xor(ay[m], off);
            az[m] += __shfl_xor(az[m], off);
        }
    }

    if (lane == 0) {
        float* o = out + (b * NPART + i0) * 3;
        #pragma unroll
        for (int m = 0; m < MI; ++m) {
            o[3 * m + 0] = L * (pi[m].x + ax[m]);
            o[3 * m + 1] = L * (pi[m].y + ay[m]);
            o[3 * m + 2] = L * (pi[m].z + az[m]);
        }
    }
}

extern "C" void kernel_launch(void* const* d_in, const int* in_sizes, int n_in,
                              void* d_out, int out_size, void* d_ws, size_t ws_size,
                              hipStream_t stream) {
    (void)in_sizes; (void)n_in; (void)d_ws; (void)ws_size; (void)out_size;
    const float* x = (const float*)d_in[0];
    float* out     = (float*)d_out;

    const double Ld   = cbrt(2048.0 / 0.016355);
    const double t    = 2.6 / Ld;
    const double Kd   = -(t * t * t * t * t) * 1.4426950408889634;  // -log2(e)*(2.6/L)^5
    const float  L    = (float)Ld;
    const float  invL = (float)(1.0 / Ld);
    const float  K    = (float)Kd;

    const int nblocks = 8 * (NPART / IPB);   // 512 blocks = 2 per CU, single round
    backflow_kernel<<<nblocks, BLOCK, 0, stream>>>(x, out, L, invL, K);
}